// Round 5
// baseline (608.642 us; speedup 1.0000x reference)
//
#include <hip/hip_runtime.h>

#define NN 100000
#define DD 128
#define RP_PAD 100004   // row_ptr/cursor stride, padded for 16B alignment

typedef short bf16x8 __attribute__((ext_vector_type(8)));
typedef float f32x4  __attribute__((ext_vector_type(4)));

__device__ __forceinline__ unsigned f2bf_rne(float f) {
    unsigned u = __float_as_uint(f);
    return (u + 0x7FFFu + ((u >> 16) & 1u)) >> 16;
}
__device__ __forceinline__ unsigned packbf(float a, float b) {
    return f2bf_rne(a) | (f2bf_rne(b) << 16);
}
__device__ __forceinline__ float bf_lo(unsigned u) { return __uint_as_float(u << 16); }
__device__ __forceinline__ float bf_hi(unsigned u) { return __uint_as_float(u & 0xFFFF0000u); }

// ---------------------------------------------------------------------------
// CSR build: histogram -> 2-level scan -> scatter (row-sorted packed edges)
// ---------------------------------------------------------------------------
__global__ __launch_bounds__(256) void hist_rows(
    const int* __restrict__ row, int* __restrict__ cnt, int E)
{
    int e = blockIdx.x * 256 + threadIdx.x;
    if (e < E) atomicAdd(&cnt[row[e]], 1);
}

__global__ __launch_bounds__(256) void scan_partial(
    const int* __restrict__ cnt, int* __restrict__ blocksum, int N)
{
    int t = threadIdx.x;
    int gbase = blockIdx.x * 1024 + t * 4;
    int s = 0;
    if (gbase + 3 < N) {
        int4 v = *(const int4*)(cnt + gbase);
        s = v.x + v.y + v.z + v.w;
    } else {
        for (int i = 0; i < 4; i++) if (gbase + i < N) s += cnt[gbase + i];
    }
    #pragma unroll
    for (int m = 1; m < 64; m <<= 1) s += __shfl_xor(s, m, 64);
    __shared__ int ws[4];
    if ((t & 63) == 0) ws[t >> 6] = s;
    __syncthreads();
    if (t == 0) blocksum[blockIdx.x] = ws[0] + ws[1] + ws[2] + ws[3];
}

__global__ __launch_bounds__(128) void scan_mid(
    int* __restrict__ blocksum, int* __restrict__ row_ptr, int nblocks, int N)
{
    __shared__ int sh[128];
    int t = threadIdx.x;
    int v = (t < nblocks) ? blocksum[t] : 0;
    sh[t] = v;
    __syncthreads();
    for (int off = 1; off < 128; off <<= 1) {
        int u = (t >= off) ? sh[t - off] : 0;
        __syncthreads();
        sh[t] += u;
        __syncthreads();
    }
    if (t < nblocks) blocksum[t] = sh[t] - v;   // exclusive
    if (t == 127) row_ptr[N] = sh[127];
}

__global__ __launch_bounds__(256) void scan_local(
    const int* __restrict__ cnt, const int* __restrict__ blocksum,
    int* __restrict__ row_ptr, int* __restrict__ cursor, int N)
{
    int t = threadIdx.x;
    int gbase = blockIdx.x * 1024 + t * 4;
    int4 raw = make_int4(0, 0, 0, 0);
    if (gbase + 3 < N) {
        raw = *(const int4*)(cnt + gbase);
    } else {
        int* p = (int*)&raw;
        for (int i = 0; i < 4; i++) p[i] = (gbase + i < N) ? cnt[gbase + i] : 0;
    }
    int s = raw.x + raw.y + raw.z + raw.w;

    int lane = t & 63;
    int inc = s;
    #pragma unroll
    for (int off = 1; off < 64; off <<= 1) {
        int u = __shfl_up(inc, off, 64);
        if (lane >= off) inc += u;
    }
    __shared__ int wsum[4];
    if (lane == 63) wsum[t >> 6] = inc;
    __syncthreads();
    int woff = 0;
    int wid = t >> 6;
    for (int i = 0; i < wid; i++) woff += wsum[i];
    int excl = woff + inc - s;
    int base = blocksum[blockIdx.x] + excl;

    int r0 = base;
    int r1 = r0 + raw.x;
    int r2 = r1 + raw.y;
    int r3 = r2 + raw.z;
    if (gbase + 3 < N) {
        int4 o = make_int4(r0, r1, r2, r3);
        *(int4*)(row_ptr + gbase) = o;
        *(int4*)(cursor + gbase)  = o;
    } else {
        int o[4] = {r0, r1, r2, r3};
        for (int i = 0; i < 4; i++) if (gbase + i < N) {
            row_ptr[gbase + i] = o[i];
            cursor[gbase + i]  = o[i];
        }
    }
}

// Packed edge scatter: one 8B (col, val) store per edge instead of 2x4B
// into separate arrays -> halves the randomly-touched cache lines.
__global__ __launch_bounds__(256) void scatter_edges(
    const int* __restrict__ row, const int* __restrict__ col,
    const float* __restrict__ vals, int* __restrict__ cursor,
    int2* __restrict__ ep, int E)
{
    int e = blockIdx.x * 256 + threadIdx.x;
    if (e < E) {
        int r = row[e];
        int p = atomicAdd(&cursor[r], 1);
        ep[p] = make_int2(col[e], __float_as_int(vals[e]));
    }
}

// ---------------------------------------------------------------------------
// Converters
// ---------------------------------------------------------------------------
__global__ __launch_bounds__(256) void cvt_bf16(
    const float4* __restrict__ in, uint4* __restrict__ out, int n8)
{
    int t = blockIdx.x * 256 + threadIdx.x;
    if (t >= n8) return;
    float4 a = in[t * 2], b = in[t * 2 + 1];
    uint4 o;
    o.x = packbf(a.x, a.y); o.y = packbf(a.z, a.w);
    o.z = packbf(b.x, b.y); o.w = packbf(b.z, b.w);
    out[t] = o;
}

// W[k][n] f32 -> Wt[n][k] bf16 (one 128x128 matrix; 2048 threads)
__global__ __launch_bounds__(256) void cvt_w(
    const float* __restrict__ W, unsigned short* __restrict__ Wt)
{
    int idx = blockIdx.x * 256 + threadIdx.x;   // 0..2047
    int n = idx >> 4;
    int kc = (idx & 15) * 8;
    unsigned r[4];
    #pragma unroll
    for (int j = 0; j < 4; j++) {
        float a = W[(kc + 2 * j) * DD + n];
        float b = W[(kc + 2 * j + 1) * DD + n];
        r[j] = packbf(a, b);
    }
    *(uint4*)(Wt + n * DD + kc) = make_uint4(r[0], r[1], r[2], r[3]);
}

// ---------------------------------------------------------------------------
// Gather SpMM (CSR, bf16, packed edges): one row per 16-lane group,
// 8 bf16 (16B) per lane. fp32 accumulate, bf16 output. Unroll 8 for MLP.
// ---------------------------------------------------------------------------
__device__ __forceinline__ void accum8(float* acc, uint4 u, float v) {
    acc[0] += v * bf_lo(u.x); acc[1] += v * bf_hi(u.x);
    acc[2] += v * bf_lo(u.y); acc[3] += v * bf_hi(u.y);
    acc[4] += v * bf_lo(u.z); acc[5] += v * bf_hi(u.z);
    acc[6] += v * bf_lo(u.w); acc[7] += v * bf_hi(u.w);
}

__global__ __launch_bounds__(256) void spmm_bf16(
    const uint4* __restrict__ x, const int* __restrict__ row_ptr,
    const int2* __restrict__ ep, uint4* __restrict__ out, int N)
{
    int t = blockIdx.x * 256 + threadIdx.x;
    int g = t >> 4;
    int lane = t & 15;
    if (g >= N) return;

    int s = row_ptr[g];
    int e = row_ptr[g + 1];
    float acc[8] = {0.f, 0.f, 0.f, 0.f, 0.f, 0.f, 0.f, 0.f};

    int k = s;
    for (; k + 8 <= e; k += 8) {
        int2 E0 = ep[k + 0], E1 = ep[k + 1], E2 = ep[k + 2], E3 = ep[k + 3];
        int2 E4 = ep[k + 4], E5 = ep[k + 5], E6 = ep[k + 6], E7 = ep[k + 7];
        uint4 X0 = x[(size_t)E0.x * 16 + lane];
        uint4 X1 = x[(size_t)E1.x * 16 + lane];
        uint4 X2 = x[(size_t)E2.x * 16 + lane];
        uint4 X3 = x[(size_t)E3.x * 16 + lane];
        uint4 X4 = x[(size_t)E4.x * 16 + lane];
        uint4 X5 = x[(size_t)E5.x * 16 + lane];
        uint4 X6 = x[(size_t)E6.x * 16 + lane];
        uint4 X7 = x[(size_t)E7.x * 16 + lane];
        accum8(acc, X0, __int_as_float(E0.y));
        accum8(acc, X1, __int_as_float(E1.y));
        accum8(acc, X2, __int_as_float(E2.y));
        accum8(acc, X3, __int_as_float(E3.y));
        accum8(acc, X4, __int_as_float(E4.y));
        accum8(acc, X5, __int_as_float(E5.y));
        accum8(acc, X6, __int_as_float(E6.y));
        accum8(acc, X7, __int_as_float(E7.y));
    }
    for (; k + 4 <= e; k += 4) {
        int2 E0 = ep[k + 0], E1 = ep[k + 1], E2 = ep[k + 2], E3 = ep[k + 3];
        uint4 X0 = x[(size_t)E0.x * 16 + lane];
        uint4 X1 = x[(size_t)E1.x * 16 + lane];
        uint4 X2 = x[(size_t)E2.x * 16 + lane];
        uint4 X3 = x[(size_t)E3.x * 16 + lane];
        accum8(acc, X0, __int_as_float(E0.y));
        accum8(acc, X1, __int_as_float(E1.y));
        accum8(acc, X2, __int_as_float(E2.y));
        accum8(acc, X3, __int_as_float(E3.y));
    }
    for (; k < e; k++) {
        int2 E0 = ep[k];
        uint4 X0 = x[(size_t)E0.x * 16 + lane];
        accum8(acc, X0, __int_as_float(E0.y));
    }

    uint4 o;
    o.x = packbf(acc[0], acc[1]); o.y = packbf(acc[2], acc[3]);
    o.z = packbf(acc[4], acc[5]); o.w = packbf(acc[6], acc[7]);
    out[(size_t)g * 16 + lane] = o;
}

// ---------------------------------------------------------------------------
// Fused dense via bf16 MFMA 16x16x32, persistent blocks + LDS-staged B.
// Block = 4 waves; per slab-iter each wave does 16 rows x 128 cols.
// Orders 0,1: B-frags from 64KB LDS (staged once per block, layout [kc][n]
// 16B cells -> 16 lanes of a quad read 256B contiguous = conflict-free-ish).
// Order 2: B-frags direct from global (L1-hot, 32KB).
// Per-row batchnorm via C-layout + shfl_xor{1,2,4,8}.
// ---------------------------------------------------------------------------
__device__ __forceinline__ void bn_accum(
    f32x4* acc, const float* __restrict__ bias, const float* __restrict__ off,
    const float* __restrict__ sc, int i, float facc[8][4])
{
    float bc[8], sv[8], ov[8];
    #pragma unroll
    for (int ct = 0; ct < 8; ct++) {
        int c = ct * 16 + i;
        bc[ct] = bias[c]; sv[ct] = sc[c]; ov[ct] = off[c];
    }
    float s[4] = {0.f, 0.f, 0.f, 0.f};
    float qq[4] = {0.f, 0.f, 0.f, 0.f};
    #pragma unroll
    for (int ct = 0; ct < 8; ct++) {
        #pragma unroll
        for (int r = 0; r < 4; r++) {
            float v = fmaxf(acc[ct][r] + bc[ct], 0.f);
            acc[ct][r] = v;
            s[r] += v;
            qq[r] += v * v;
        }
    }
    #pragma unroll
    for (int r = 0; r < 4; r++) {
        #pragma unroll
        for (int m = 1; m <= 8; m <<= 1) {
            s[r]  += __shfl_xor(s[r],  m, 64);
            qq[r] += __shfl_xor(qq[r], m, 64);
        }
    }
    #pragma unroll
    for (int r = 0; r < 4; r++) {
        float mn = s[r] * 0.0078125f;
        float var = qq[r] * 0.0078125f - mn * mn;
        float rs = rsqrtf(var + 1e-9f);
        #pragma unroll
        for (int ct = 0; ct < 8; ct++)
            facc[ct][r] += sv[ct] * (acc[ct][r] - mn) * rs + ov[ct];
    }
}

__global__ __launch_bounds__(256) void fused_dense_mfma(
    const unsigned short* __restrict__ h0,
    const unsigned short* __restrict__ h1,
    const unsigned short* __restrict__ h2,
    const unsigned short* __restrict__ Wt,   // [3][128][128] bf16, [o][n][k]
    const float* __restrict__ b0, const float* __restrict__ b1,
    const float* __restrict__ b2,
    const float* __restrict__ off0, const float* __restrict__ off1,
    const float* __restrict__ off2,
    const float* __restrict__ sc0, const float* __restrict__ sc1,
    const float* __restrict__ sc2,
    float* __restrict__ out, int N, int nslab)
{
    __shared__ uint4 Bl[4096];   // 64 KB: orders 0,1; cell (kc,n) at kc*128+n

    const int tid  = threadIdx.x;
    const int wave = tid >> 6;
    const int lane = tid & 63;
    const int i    = lane & 15;   // tile col / A-row
    const int q    = lane >> 4;   // quad
    const int n    = 0;           // (unused placeholder)
    (void)n;

    // Stage W^T for orders 0,1 into LDS (once per block).
    #pragma unroll
    for (int o = 0; o < 2; o++) {
        const uint4* Wg = (const uint4*)(Wt + o * DD * DD);
        #pragma unroll
        for (int j = 0; j < 8; j++) {
            int c  = j * 256 + tid;      // 0..2047
            int nn = c & 127;            // col index n
            int kc = c >> 7;             // 16B k-chunk 0..15
            Bl[o * 2048 + kc * 128 + nn] = Wg[nn * 16 + kc];
        }
    }
    __syncthreads();

    const unsigned short* hops[3] = {h0, h1, h2};
    const float* bs[3]  = {b0, b1, b2};
    const float* ofs[3] = {off0, off1, off2};
    const float* scs[3] = {sc0, sc1, sc2};
    const bf16x8* Bv = (const bf16x8*)Bl;

    for (int sb = blockIdx.x; sb < nslab; sb += gridDim.x) {
        const int slab = sb * 64 + wave * 16;
        int arow = slab + i;
        if (arow >= N) arow = N - 1;

        float facc[8][4];
        #pragma unroll
        for (int ct = 0; ct < 8; ct++)
            #pragma unroll
            for (int r = 0; r < 4; r++) facc[ct][r] = 0.f;

        // Orders 0,1: B from LDS
        #pragma unroll
        for (int o = 0; o < 2; o++) {
            const unsigned short* arow_p = hops[o] + (size_t)arow * DD + q * 8;
            f32x4 acc[8];
            #pragma unroll
            for (int ct = 0; ct < 8; ct++) acc[ct] = (f32x4){0.f, 0.f, 0.f, 0.f};
            #pragma unroll
            for (int kb = 0; kb < 4; kb++) {
                bf16x8 a = *(const bf16x8*)(arow_p + kb * 32);
                const int kc = kb * 4 + q;
                #pragma unroll
                for (int ct = 0; ct < 8; ct++) {
                    bf16x8 b = Bv[o * 2048 + kc * 128 + ct * 16 + i];
                    acc[ct] = __builtin_amdgcn_mfma_f32_16x16x32_bf16(a, b, acc[ct], 0, 0, 0);
                }
            }
            bn_accum(acc, bs[o], ofs[o], scs[o], i, facc);
        }

        // Order 2: B from global (L1-hot)
        {
            const unsigned short* Wo = Wt + 2 * (DD * DD);
            const unsigned short* arow_p = hops[2] + (size_t)arow * DD + q * 8;
            f32x4 acc[8];
            #pragma unroll
            for (int ct = 0; ct < 8; ct++) acc[ct] = (f32x4){0.f, 0.f, 0.f, 0.f};
            #pragma unroll
            for (int kb = 0; kb < 4; kb++) {
                bf16x8 a = *(const bf16x8*)(arow_p + kb * 32);
                #pragma unroll
                for (int ct = 0; ct < 8; ct++) {
                    bf16x8 b = *(const bf16x8*)(Wo + (ct * 16 + i) * DD + kb * 32 + q * 8);
                    acc[ct] = __builtin_amdgcn_mfma_f32_16x16x32_bf16(a, b, acc[ct], 0, 0, 0);
                }
            }
            bn_accum(acc, bs[2], ofs[2], scs[2], i, facc);
        }

        // Store: lane holds rows slab+q*4+r, cols ct*16+i
        #pragma unroll
        for (int r = 0; r < 4; r++) {
            int orow = slab + q * 4 + r;
            if (orow < N) {
                float* op = out + (size_t)orow * DD + i;
                #pragma unroll
                for (int ct = 0; ct < 8; ct++) op[ct * 16] = facc[ct][r];
            }
        }
    }
}

extern "C" void kernel_launch(void* const* d_in, const int* in_sizes, int n_in,
                              void* d_out, int out_size, void* d_ws, size_t ws_size,
                              hipStream_t stream)
{
    const float* vecs = (const float*)d_in[0];
    const float* adj  = (const float*)d_in[1];
    const int*   row  = (const int*)d_in[2];
    const int*   col  = (const int*)d_in[3];
    const float* W0   = (const float*)d_in[4];
    const float* b0   = (const float*)d_in[5];
    const float* off0 = (const float*)d_in[6];
    const float* sc0  = (const float*)d_in[7];
    const float* W1   = (const float*)d_in[8];
    const float* b1   = (const float*)d_in[9];
    const float* off1 = (const float*)d_in[10];
    const float* sc1  = (const float*)d_in[11];
    const float* W2   = (const float*)d_in[12];
    const float* b2   = (const float*)d_in[13];
    const float* off2 = (const float*)d_in[14];
    const float* sc2  = (const float*)d_in[15];

    const int E = in_sizes[1];
    const int N = NN;

    // Workspace layout (all 16B-aligned)
    unsigned short* hop1_bf = (unsigned short*)d_ws;          // N*128 bf16
    unsigned short* hop2_bf = hop1_bf + (size_t)N * DD;       // N*128 bf16
    unsigned short* vecs_bf = hop2_bf + (size_t)N * DD;       // N*128 bf16
    unsigned short* Wt_bf   = vecs_bf + (size_t)N * DD;       // 3*128*128 bf16
    int*   row_ptr  = (int*)(Wt_bf + 3 * DD * DD);            // RP_PAD
    int*   cursor   = row_ptr + RP_PAD;                       // RP_PAD
    int2*  epack    = (int2*)(cursor + RP_PAD);               // E (8B each)
    int*   blocksum = (int*)(epack + E);                      // <=128

    hipMemsetAsync(cursor, 0, (size_t)N * sizeof(int), stream);

    // Converters (independent of CSR build)
    const int n8 = N * DD / 8;
    cvt_bf16<<<(n8 + 255) / 256, 256, 0, stream>>>(
        (const float4*)vecs, (uint4*)vecs_bf, n8);
    cvt_w<<<8, 256, 0, stream>>>(W0, Wt_bf);
    cvt_w<<<8, 256, 0, stream>>>(W1, Wt_bf + DD * DD);
    cvt_w<<<8, 256, 0, stream>>>(W2, Wt_bf + 2 * DD * DD);

    // CSR build
    const int snb = (N + 1023) / 1024;
    int eb = (E + 255) / 256;
    hist_rows<<<eb, 256, 0, stream>>>(row, cursor, E);
    scan_partial<<<snb, 256, 0, stream>>>(cursor, blocksum, N);
    scan_mid<<<1, 128, 0, stream>>>(blocksum, row_ptr, snb, N);
    scan_local<<<snb, 256, 0, stream>>>(cursor, blocksum, row_ptr, cursor, N);
    scatter_edges<<<eb, 256, 0, stream>>>(row, col, adj, cursor, epack, E);

    // SpMM hops (bf16 in/out, fp32 accumulate)
    int sb = (N * 16 + 255) / 256;
    spmm_bf16<<<sb, 256, 0, stream>>>(
        (const uint4*)vecs_bf, row_ptr, epack, (uint4*)hop1_bf, N);
    spmm_bf16<<<sb, 256, 0, stream>>>(
        (const uint4*)hop1_bf, row_ptr, epack, (uint4*)hop2_bf, N);

    // Fused dense (MFMA, persistent blocks, LDS-staged B for orders 0,1)
    const int nslab = (N + 63) / 64;   // 1563
    fused_dense_mfma<<<512, 256, 0, stream>>>(
        vecs_bf, hop1_bf, hop2_bf, Wt_bf,
        b0, b1, b2, off0, off1, off2, sc0, sc1, sc2,
        (float*)d_out, N, nslab);
}

// Round 6
// 508.217 us; speedup vs baseline: 1.1976x; 1.1976x over previous
//
#include <hip/hip_runtime.h>

#define NN 100000
#define DD 128
#define RP_PAD 100004   // row_ptr/cursor stride, padded for 16B alignment

typedef short bf16x8 __attribute__((ext_vector_type(8)));
typedef float f32x4  __attribute__((ext_vector_type(4)));

__device__ __forceinline__ unsigned f2bf_rne(float f) {
    unsigned u = __float_as_uint(f);
    return (u + 0x7FFFu + ((u >> 16) & 1u)) >> 16;
}
__device__ __forceinline__ unsigned packbf(float a, float b) {
    return f2bf_rne(a) | (f2bf_rne(b) << 16);
}
__device__ __forceinline__ float bf_lo(unsigned u) { return __uint_as_float(u << 16); }
__device__ __forceinline__ float bf_hi(unsigned u) { return __uint_as_float(u & 0xFFFF0000u); }

// ---------------------------------------------------------------------------
// CSR build: histogram -> 2-level scan -> scatter (row-sorted packed edges)
// ---------------------------------------------------------------------------
__global__ __launch_bounds__(256) void hist_rows(
    const int* __restrict__ row, int* __restrict__ cnt, int E)
{
    int e = blockIdx.x * 256 + threadIdx.x;
    if (e < E) atomicAdd(&cnt[row[e]], 1);
}

__global__ __launch_bounds__(256) void scan_partial(
    const int* __restrict__ cnt, int* __restrict__ blocksum, int N)
{
    int t = threadIdx.x;
    int gbase = blockIdx.x * 1024 + t * 4;
    int s = 0;
    if (gbase + 3 < N) {
        int4 v = *(const int4*)(cnt + gbase);
        s = v.x + v.y + v.z + v.w;
    } else {
        for (int i = 0; i < 4; i++) if (gbase + i < N) s += cnt[gbase + i];
    }
    #pragma unroll
    for (int m = 1; m < 64; m <<= 1) s += __shfl_xor(s, m, 64);
    __shared__ int ws[4];
    if ((t & 63) == 0) ws[t >> 6] = s;
    __syncthreads();
    if (t == 0) blocksum[blockIdx.x] = ws[0] + ws[1] + ws[2] + ws[3];
}

__global__ __launch_bounds__(128) void scan_mid(
    int* __restrict__ blocksum, int* __restrict__ row_ptr, int nblocks, int N)
{
    __shared__ int sh[128];
    int t = threadIdx.x;
    int v = (t < nblocks) ? blocksum[t] : 0;
    sh[t] = v;
    __syncthreads();
    for (int off = 1; off < 128; off <<= 1) {
        int u = (t >= off) ? sh[t - off] : 0;
        __syncthreads();
        sh[t] += u;
        __syncthreads();
    }
    if (t < nblocks) blocksum[t] = sh[t] - v;   // exclusive
    if (t == 127) row_ptr[N] = sh[127];
}

__global__ __launch_bounds__(256) void scan_local(
    const int* __restrict__ cnt, const int* __restrict__ blocksum,
    int* __restrict__ row_ptr, int* __restrict__ cursor, int N)
{
    int t = threadIdx.x;
    int gbase = blockIdx.x * 1024 + t * 4;
    int4 raw = make_int4(0, 0, 0, 0);
    if (gbase + 3 < N) {
        raw = *(const int4*)(cnt + gbase);
    } else {
        int* p = (int*)&raw;
        for (int i = 0; i < 4; i++) p[i] = (gbase + i < N) ? cnt[gbase + i] : 0;
    }
    int s = raw.x + raw.y + raw.z + raw.w;

    int lane = t & 63;
    int inc = s;
    #pragma unroll
    for (int off = 1; off < 64; off <<= 1) {
        int u = __shfl_up(inc, off, 64);
        if (lane >= off) inc += u;
    }
    __shared__ int wsum[4];
    if (lane == 63) wsum[t >> 6] = inc;
    __syncthreads();
    int woff = 0;
    int wid = t >> 6;
    for (int i = 0; i < wid; i++) woff += wsum[i];
    int excl = woff + inc - s;
    int base = blocksum[blockIdx.x] + excl;

    int r0 = base;
    int r1 = r0 + raw.x;
    int r2 = r1 + raw.y;
    int r3 = r2 + raw.z;
    if (gbase + 3 < N) {
        int4 o = make_int4(r0, r1, r2, r3);
        *(int4*)(row_ptr + gbase) = o;
        *(int4*)(cursor + gbase)  = o;
    } else {
        int o[4] = {r0, r1, r2, r3};
        for (int i = 0; i < 4; i++) if (gbase + i < N) {
            row_ptr[gbase + i] = o[i];
            cursor[gbase + i]  = o[i];
        }
    }
}

// Packed edge scatter: one 8B (col, val) store per edge instead of 2x4B
// into separate arrays -> halves the randomly-touched cache lines.
__global__ __launch_bounds__(256) void scatter_edges(
    const int* __restrict__ row, const int* __restrict__ col,
    const float* __restrict__ vals, int* __restrict__ cursor,
    int2* __restrict__ ep, int E)
{
    int e = blockIdx.x * 256 + threadIdx.x;
    if (e < E) {
        int r = row[e];
        int p = atomicAdd(&cursor[r], 1);
        ep[p] = make_int2(col[e], __float_as_int(vals[e]));
    }
}

// ---------------------------------------------------------------------------
// Converters
// ---------------------------------------------------------------------------
__global__ __launch_bounds__(256) void cvt_bf16(
    const float4* __restrict__ in, uint4* __restrict__ out, int n8)
{
    int t = blockIdx.x * 256 + threadIdx.x;
    if (t >= n8) return;
    float4 a = in[t * 2], b = in[t * 2 + 1];
    uint4 o;
    o.x = packbf(a.x, a.y); o.y = packbf(a.z, a.w);
    o.z = packbf(b.x, b.y); o.w = packbf(b.z, b.w);
    out[t] = o;
}

// W[k][n] f32 -> Wt[n][k] bf16 (one 128x128 matrix; 2048 threads)
__global__ __launch_bounds__(256) void cvt_w(
    const float* __restrict__ W, unsigned short* __restrict__ Wt)
{
    int idx = blockIdx.x * 256 + threadIdx.x;   // 0..2047
    int n = idx >> 4;
    int kc = (idx & 15) * 8;
    unsigned r[4];
    #pragma unroll
    for (int j = 0; j < 4; j++) {
        float a = W[(kc + 2 * j) * DD + n];
        float b = W[(kc + 2 * j + 1) * DD + n];
        r[j] = packbf(a, b);
    }
    *(uint4*)(Wt + n * DD + kc) = make_uint4(r[0], r[1], r[2], r[3]);
}

// ---------------------------------------------------------------------------
// Gather SpMM (CSR, bf16, packed edges): one row per 16-lane group,
// 8 bf16 (16B) per lane. fp32 accumulate, bf16 output. Unroll 8 for MLP.
// ---------------------------------------------------------------------------
__device__ __forceinline__ void accum8(float* acc, uint4 u, float v) {
    acc[0] += v * bf_lo(u.x); acc[1] += v * bf_hi(u.x);
    acc[2] += v * bf_lo(u.y); acc[3] += v * bf_hi(u.y);
    acc[4] += v * bf_lo(u.z); acc[5] += v * bf_hi(u.z);
    acc[6] += v * bf_lo(u.w); acc[7] += v * bf_hi(u.w);
}

__global__ __launch_bounds__(256) void spmm_bf16(
    const uint4* __restrict__ x, const int* __restrict__ row_ptr,
    const int2* __restrict__ ep, uint4* __restrict__ out, int N)
{
    int t = blockIdx.x * 256 + threadIdx.x;
    int g = t >> 4;
    int lane = t & 15;
    if (g >= N) return;

    int s = row_ptr[g];
    int e = row_ptr[g + 1];
    float acc[8] = {0.f, 0.f, 0.f, 0.f, 0.f, 0.f, 0.f, 0.f};

    int k = s;
    for (; k + 8 <= e; k += 8) {
        int2 E0 = ep[k + 0], E1 = ep[k + 1], E2 = ep[k + 2], E3 = ep[k + 3];
        int2 E4 = ep[k + 4], E5 = ep[k + 5], E6 = ep[k + 6], E7 = ep[k + 7];
        uint4 X0 = x[(size_t)E0.x * 16 + lane];
        uint4 X1 = x[(size_t)E1.x * 16 + lane];
        uint4 X2 = x[(size_t)E2.x * 16 + lane];
        uint4 X3 = x[(size_t)E3.x * 16 + lane];
        uint4 X4 = x[(size_t)E4.x * 16 + lane];
        uint4 X5 = x[(size_t)E5.x * 16 + lane];
        uint4 X6 = x[(size_t)E6.x * 16 + lane];
        uint4 X7 = x[(size_t)E7.x * 16 + lane];
        accum8(acc, X0, __int_as_float(E0.y));
        accum8(acc, X1, __int_as_float(E1.y));
        accum8(acc, X2, __int_as_float(E2.y));
        accum8(acc, X3, __int_as_float(E3.y));
        accum8(acc, X4, __int_as_float(E4.y));
        accum8(acc, X5, __int_as_float(E5.y));
        accum8(acc, X6, __int_as_float(E6.y));
        accum8(acc, X7, __int_as_float(E7.y));
    }
    for (; k + 4 <= e; k += 4) {
        int2 E0 = ep[k + 0], E1 = ep[k + 1], E2 = ep[k + 2], E3 = ep[k + 3];
        uint4 X0 = x[(size_t)E0.x * 16 + lane];
        uint4 X1 = x[(size_t)E1.x * 16 + lane];
        uint4 X2 = x[(size_t)E2.x * 16 + lane];
        uint4 X3 = x[(size_t)E3.x * 16 + lane];
        accum8(acc, X0, __int_as_float(E0.y));
        accum8(acc, X1, __int_as_float(E1.y));
        accum8(acc, X2, __int_as_float(E2.y));
        accum8(acc, X3, __int_as_float(E3.y));
    }
    for (; k < e; k++) {
        int2 E0 = ep[k];
        uint4 X0 = x[(size_t)E0.x * 16 + lane];
        accum8(acc, X0, __int_as_float(E0.y));
    }

    uint4 o;
    o.x = packbf(acc[0], acc[1]); o.y = packbf(acc[2], acc[3]);
    o.z = packbf(acc[4], acc[5]); o.w = packbf(acc[6], acc[7]);
    out[(size_t)g * 16 + lane] = o;
}

// ---------------------------------------------------------------------------
// Fused dense via bf16 MFMA 16x16x32. One 64-row slab per block (4 waves x
// 16 rows). Per order: stage W^T (32 KB) into LDS in [kc][n] layout (16B
// cells; 16 lanes read 256B contiguous -> 2-way bank aliasing = free), then
// B-frags from LDS, A-frags direct from global (read-once).
// Per-row batchnorm via C-layout + shfl_xor{1,2,4,8}.
// No persistent loop -> low live state -> no VGPR spills (round-5 lesson).
// ---------------------------------------------------------------------------
__device__ __forceinline__ void bn_accum(
    f32x4* acc, const float* __restrict__ bias, const float* __restrict__ off,
    const float* __restrict__ sc, int i, float facc[8][4])
{
    float bc[8], sv[8], ov[8];
    #pragma unroll
    for (int ct = 0; ct < 8; ct++) {
        int c = ct * 16 + i;
        bc[ct] = bias[c]; sv[ct] = sc[c]; ov[ct] = off[c];
    }
    float s[4] = {0.f, 0.f, 0.f, 0.f};
    float qq[4] = {0.f, 0.f, 0.f, 0.f};
    #pragma unroll
    for (int ct = 0; ct < 8; ct++) {
        #pragma unroll
        for (int r = 0; r < 4; r++) {
            float v = fmaxf(acc[ct][r] + bc[ct], 0.f);
            acc[ct][r] = v;
            s[r] += v;
            qq[r] += v * v;
        }
    }
    #pragma unroll
    for (int r = 0; r < 4; r++) {
        #pragma unroll
        for (int m = 1; m <= 8; m <<= 1) {
            s[r]  += __shfl_xor(s[r],  m, 64);
            qq[r] += __shfl_xor(qq[r], m, 64);
        }
    }
    #pragma unroll
    for (int r = 0; r < 4; r++) {
        float mn = s[r] * 0.0078125f;
        float var = qq[r] * 0.0078125f - mn * mn;
        float rs = rsqrtf(var + 1e-9f);
        #pragma unroll
        for (int ct = 0; ct < 8; ct++)
            facc[ct][r] += sv[ct] * (acc[ct][r] - mn) * rs + ov[ct];
    }
}

__global__ __launch_bounds__(256) void fused_dense_mfma(
    const unsigned short* __restrict__ h0,
    const unsigned short* __restrict__ h1,
    const unsigned short* __restrict__ h2,
    const unsigned short* __restrict__ Wt,   // [3][128][128] bf16, [o][n][k]
    const float* __restrict__ b0, const float* __restrict__ b1,
    const float* __restrict__ b2,
    const float* __restrict__ off0, const float* __restrict__ off1,
    const float* __restrict__ off2,
    const float* __restrict__ sc0, const float* __restrict__ sc1,
    const float* __restrict__ sc2,
    float* __restrict__ out, int N)
{
    __shared__ uint4 Bl[2048];   // 32 KB: current order's W^T, cell (kc,n) at kc*128+n

    const int tid  = threadIdx.x;
    const int wave = tid >> 6;
    const int lane = tid & 63;
    const int i    = lane & 15;   // tile col / A-row
    const int q    = lane >> 4;   // quad
    const int slab = blockIdx.x * 64 + wave * 16;

    int arow = slab + i;
    if (arow >= N) arow = N - 1;

    const unsigned short* hops[3] = {h0, h1, h2};
    const float* bs[3]  = {b0, b1, b2};
    const float* ofs[3] = {off0, off1, off2};
    const float* scs[3] = {sc0, sc1, sc2};
    const bf16x8* Bv = (const bf16x8*)Bl;

    float facc[8][4];
    #pragma unroll
    for (int ct = 0; ct < 8; ct++)
        #pragma unroll
        for (int r = 0; r < 4; r++) facc[ct][r] = 0.f;

    for (int o = 0; o < 3; o++) {
        // Stage this order's W^T into LDS, [kc][n] layout.
        const uint4* Wg = (const uint4*)(Wt + o * DD * DD);
        #pragma unroll
        for (int j = 0; j < 8; j++) {
            int c  = j * 256 + tid;      // 0..2047
            int nn = c & 127;
            int kc = c >> 7;
            Bl[kc * 128 + nn] = Wg[nn * 16 + kc];
        }
        __syncthreads();

        const unsigned short* arow_p = hops[o] + (size_t)arow * DD + q * 8;
        f32x4 acc[8];
        #pragma unroll
        for (int ct = 0; ct < 8; ct++) acc[ct] = (f32x4){0.f, 0.f, 0.f, 0.f};
        #pragma unroll
        for (int kb = 0; kb < 4; kb++) {
            bf16x8 a = *(const bf16x8*)(arow_p + kb * 32);
            const int kc = kb * 4 + q;
            #pragma unroll
            for (int ct = 0; ct < 8; ct++) {
                bf16x8 b = Bv[kc * 128 + ct * 16 + i];
                acc[ct] = __builtin_amdgcn_mfma_f32_16x16x32_bf16(a, b, acc[ct], 0, 0, 0);
            }
        }
        bn_accum(acc, bs[o], ofs[o], scs[o], i, facc);
        __syncthreads();   // protect LDS before next order restages
    }

    // Store: lane holds rows slab+q*4+r, cols ct*16+i
    #pragma unroll
    for (int r = 0; r < 4; r++) {
        int orow = slab + q * 4 + r;
        if (orow < N) {
            float* op = out + (size_t)orow * DD + i;
            #pragma unroll
            for (int ct = 0; ct < 8; ct++) op[ct * 16] = facc[ct][r];
        }
    }
}

extern "C" void kernel_launch(void* const* d_in, const int* in_sizes, int n_in,
                              void* d_out, int out_size, void* d_ws, size_t ws_size,
                              hipStream_t stream)
{
    const float* vecs = (const float*)d_in[0];
    const float* adj  = (const float*)d_in[1];
    const int*   row  = (const int*)d_in[2];
    const int*   col  = (const int*)d_in[3];
    const float* W0   = (const float*)d_in[4];
    const float* b0   = (const float*)d_in[5];
    const float* off0 = (const float*)d_in[6];
    const float* sc0  = (const float*)d_in[7];
    const float* W1   = (const float*)d_in[8];
    const float* b1   = (const float*)d_in[9];
    const float* off1 = (const float*)d_in[10];
    const float* sc1  = (const float*)d_in[11];
    const float* W2   = (const float*)d_in[12];
    const float* b2   = (const float*)d_in[13];
    const float* off2 = (const float*)d_in[14];
    const float* sc2  = (const float*)d_in[15];

    const int E = in_sizes[1];
    const int N = NN;

    // Workspace layout (all 16B-aligned)
    unsigned short* hop1_bf = (unsigned short*)d_ws;          // N*128 bf16
    unsigned short* hop2_bf = hop1_bf + (size_t)N * DD;       // N*128 bf16
    unsigned short* vecs_bf = hop2_bf + (size_t)N * DD;       // N*128 bf16
    unsigned short* Wt_bf   = vecs_bf + (size_t)N * DD;       // 3*128*128 bf16
    int*   row_ptr  = (int*)(Wt_bf + 3 * DD * DD);            // RP_PAD
    int*   cursor   = row_ptr + RP_PAD;                       // RP_PAD
    int2*  epack    = (int2*)(cursor + RP_PAD);               // E (8B each)
    int*   blocksum = (int*)(epack + E);                      // <=128

    hipMemsetAsync(cursor, 0, (size_t)N * sizeof(int), stream);

    // Converters (independent of CSR build)
    const int n8 = N * DD / 8;
    cvt_bf16<<<(n8 + 255) / 256, 256, 0, stream>>>(
        (const float4*)vecs, (uint4*)vecs_bf, n8);
    cvt_w<<<8, 256, 0, stream>>>(W0, Wt_bf);
    cvt_w<<<8, 256, 0, stream>>>(W1, Wt_bf + DD * DD);
    cvt_w<<<8, 256, 0, stream>>>(W2, Wt_bf + 2 * DD * DD);

    // CSR build
    const int snb = (N + 1023) / 1024;
    int eb = (E + 255) / 256;
    hist_rows<<<eb, 256, 0, stream>>>(row, cursor, E);
    scan_partial<<<snb, 256, 0, stream>>>(cursor, blocksum, N);
    scan_mid<<<1, 128, 0, stream>>>(blocksum, row_ptr, snb, N);
    scan_local<<<snb, 256, 0, stream>>>(cursor, blocksum, row_ptr, cursor, N);
    scatter_edges<<<eb, 256, 0, stream>>>(row, col, adj, cursor, epack, E);

    // SpMM hops (bf16 in/out, fp32 accumulate)
    int sb = (N * 16 + 255) / 256;
    spmm_bf16<<<sb, 256, 0, stream>>>(
        (const uint4*)vecs_bf, row_ptr, epack, (uint4*)hop1_bf, N);
    spmm_bf16<<<sb, 256, 0, stream>>>(
        (const uint4*)hop1_bf, row_ptr, epack, (uint4*)hop2_bf, N);

    // Fused dense (MFMA, per-order LDS-staged B)
    const int db = (N + 63) / 64;   // 1563
    fused_dense_mfma<<<db, 256, 0, stream>>>(
        vecs_bf, hop1_bf, hop2_bf, Wt_bf,
        b0, b1, b2, off0, off1, off2, sc0, sc1, sc2,
        (float*)d_out, N);
}

// Round 7
// 400.466 us; speedup vs baseline: 1.5198x; 1.2691x over previous
//
#include <hip/hip_runtime.h>

#define NN 100000
#define DD 128
#define NB 391          // row buckets of 256 rows: (100000+255)>>8
#define RP_PAD 100004   // row_ptr elems, padded for 16B alignment

typedef short bf16x8 __attribute__((ext_vector_type(8)));
typedef float f32x4  __attribute__((ext_vector_type(4)));

__device__ __forceinline__ unsigned f2bf_rne(float f) {
    unsigned u = __float_as_uint(f);
    return (u + 0x7FFFu + ((u >> 16) & 1u)) >> 16;
}
__device__ __forceinline__ unsigned packbf(float a, float b) {
    return f2bf_rne(a) | (f2bf_rne(b) << 16);
}
__device__ __forceinline__ float bf_lo(unsigned u) { return __uint_as_float(u << 16); }
__device__ __forceinline__ float bf_hi(unsigned u) { return __uint_as_float(u & 0xFFFF0000u); }

// ---------------------------------------------------------------------------
// Bucketed CSR build.
// Pass 1: per-WG LDS histogram of buckets -> global bucket counts.
// ---------------------------------------------------------------------------
__global__ __launch_bounds__(256) void bucket_hist(
    const int* __restrict__ row, int* __restrict__ bcnt, int E)
{
    __shared__ int h[NB];
    for (int j = threadIdx.x; j < NB; j += 256) h[j] = 0;
    __syncthreads();
    int cb = blockIdx.x * 8192;
    int ce = min(cb + 8192, E);
    for (int j = cb + threadIdx.x; j < ce; j += 256)
        atomicAdd(&h[row[j] >> 8], 1);
    __syncthreads();
    for (int j = threadIdx.x; j < NB; j += 256)
        if (h[j]) atomicAdd(&bcnt[j], h[j]);
}

// Single block: exclusive scan of NB bucket counts -> bbase[0..NB], cursor.
__global__ __launch_bounds__(512) void bucket_scan(
    const int* __restrict__ bcnt, int* __restrict__ bbase,
    int* __restrict__ bcursor)
{
    __shared__ int sh[512];
    int t = threadIdx.x;
    int v = (t < NB) ? bcnt[t] : 0;
    sh[t] = v;
    __syncthreads();
    for (int off = 1; off < 512; off <<= 1) {
        int u = (t >= off) ? sh[t - off] : 0;
        __syncthreads();
        sh[t] += u;
        __syncthreads();
    }
    if (t < NB) {
        int b = sh[t] - v;
        bbase[t] = b;
        bcursor[t] = b;
    }
    if (t == NB - 1) bbase[NB] = sh[NB - 1];
}

// Pass 2: scatter edges into per-bucket runs. Record = (col | row_lo<<17, val).
// Per-WG: LDS count -> one cursor reservation per bucket -> LDS-cursor scatter.
// Writes land in ~21-edge dense runs per bucket -> ~6x fewer dirty lines.
__global__ __launch_bounds__(256) void bucket_scatter(
    const int* __restrict__ row, const int* __restrict__ col,
    const float* __restrict__ vals, int* __restrict__ bcursor,
    int2* __restrict__ ep_raw, int E)
{
    __shared__ int cnt[NB];
    __shared__ int base[NB];
    for (int j = threadIdx.x; j < NB; j += 256) cnt[j] = 0;
    __syncthreads();
    int cb = blockIdx.x * 8192;
    int ce = min(cb + 8192, E);
    for (int j = cb + threadIdx.x; j < ce; j += 256)
        atomicAdd(&cnt[row[j] >> 8], 1);
    __syncthreads();
    for (int j = threadIdx.x; j < NB; j += 256) {
        int c = cnt[j];
        base[j] = c ? atomicAdd(&bcursor[j], c) : 0;
        cnt[j] = 0;
    }
    __syncthreads();
    for (int j = cb + threadIdx.x; j < ce; j += 256) {
        int r = row[j];
        int b = r >> 8;
        int off = atomicAdd(&cnt[b], 1);
        unsigned meta = (unsigned)col[j] | ((unsigned)(r & 255) << 17);
        ep_raw[base[b] + off] = make_int2((int)meta, __float_as_int(vals[j]));
    }
}

// Pass 3: one WG per bucket. LDS-hist the 256 in-bucket rows, LDS scan ->
// row_ptr (coalesced), then fine-scatter records to CSR order within the
// bucket's dense (~32KB, L2-hot) span. Also strips row_lo from meta.
__global__ __launch_bounds__(256) void bucket_to_csr(
    const int* __restrict__ bbase, const int2* __restrict__ ep_raw,
    int* __restrict__ row_ptr, int2* __restrict__ ep, int N, int E)
{
    __shared__ int rcnt[256];
    __shared__ int rcur[256];
    __shared__ int wsum[4];
    const int b = blockIdx.x;
    const int t = threadIdx.x;
    const int s = bbase[b], e = bbase[b + 1];

    rcnt[t] = 0;
    __syncthreads();
    for (int j = s + t; j < e; j += 256)
        atomicAdd(&rcnt[(unsigned)ep_raw[j].x >> 17], 1);
    __syncthreads();

    // exclusive scan of 256 counts (4 wave-scans + combine)
    int v = rcnt[t];
    int lane = t & 63;
    int inc = v;
    #pragma unroll
    for (int off = 1; off < 64; off <<= 1) {
        int u = __shfl_up(inc, off, 64);
        if (lane >= off) inc += u;
    }
    if (lane == 63) wsum[t >> 6] = inc;
    __syncthreads();
    int woff = 0;
    for (int i = 0; i < (t >> 6); i++) woff += wsum[i];
    int excl = woff + inc - v;

    int grow = b * 256 + t;
    if (grow < N) row_ptr[grow] = s + excl;
    rcur[t] = excl;
    __syncthreads();

    for (int j = s + t; j < e; j += 256) {
        int2 rec = ep_raw[j];
        unsigned meta = (unsigned)rec.x;
        int rlo = meta >> 17;
        int c = (int)(meta & 0x1FFFFu);
        int p = atomicAdd(&rcur[rlo], 1);
        ep[s + p] = make_int2(c, rec.y);
    }
    if (b == 0 && t == 0) row_ptr[N] = E;
}

// ---------------------------------------------------------------------------
// Converters
// ---------------------------------------------------------------------------
__global__ __launch_bounds__(256) void cvt_bf16(
    const float4* __restrict__ in, uint4* __restrict__ out, int n8)
{
    int t = blockIdx.x * 256 + threadIdx.x;
    if (t >= n8) return;
    float4 a = in[t * 2], b = in[t * 2 + 1];
    uint4 o;
    o.x = packbf(a.x, a.y); o.y = packbf(a.z, a.w);
    o.z = packbf(b.x, b.y); o.w = packbf(b.z, b.w);
    out[t] = o;
}

// W[k][n] f32 -> Wt[n][k] bf16 (one 128x128 matrix; 2048 threads)
__global__ __launch_bounds__(256) void cvt_w(
    const float* __restrict__ W, unsigned short* __restrict__ Wt)
{
    int idx = blockIdx.x * 256 + threadIdx.x;   // 0..2047
    int n = idx >> 4;
    int kc = (idx & 15) * 8;
    unsigned r[4];
    #pragma unroll
    for (int j = 0; j < 4; j++) {
        float a = W[(kc + 2 * j) * DD + n];
        float b = W[(kc + 2 * j + 1) * DD + n];
        r[j] = packbf(a, b);
    }
    *(uint4*)(Wt + n * DD + kc) = make_uint4(r[0], r[1], r[2], r[3]);
}

// ---------------------------------------------------------------------------
// Gather SpMM (CSR, bf16, packed edges): one row per 16-lane group,
// 8 bf16 (16B) per lane. fp32 accumulate, bf16 output. Unroll 8 for MLP.
// ---------------------------------------------------------------------------
__device__ __forceinline__ void accum8(float* acc, uint4 u, float v) {
    acc[0] += v * bf_lo(u.x); acc[1] += v * bf_hi(u.x);
    acc[2] += v * bf_lo(u.y); acc[3] += v * bf_hi(u.y);
    acc[4] += v * bf_lo(u.z); acc[5] += v * bf_hi(u.z);
    acc[6] += v * bf_lo(u.w); acc[7] += v * bf_hi(u.w);
}

__global__ __launch_bounds__(256) void spmm_bf16(
    const uint4* __restrict__ x, const int* __restrict__ row_ptr,
    const int2* __restrict__ ep, uint4* __restrict__ out, int N)
{
    int t = blockIdx.x * 256 + threadIdx.x;
    int g = t >> 4;
    int lane = t & 15;
    if (g >= N) return;

    int s = row_ptr[g];
    int e = row_ptr[g + 1];
    float acc[8] = {0.f, 0.f, 0.f, 0.f, 0.f, 0.f, 0.f, 0.f};

    int k = s;
    for (; k + 8 <= e; k += 8) {
        int2 E0 = ep[k + 0], E1 = ep[k + 1], E2 = ep[k + 2], E3 = ep[k + 3];
        int2 E4 = ep[k + 4], E5 = ep[k + 5], E6 = ep[k + 6], E7 = ep[k + 7];
        uint4 X0 = x[(size_t)E0.x * 16 + lane];
        uint4 X1 = x[(size_t)E1.x * 16 + lane];
        uint4 X2 = x[(size_t)E2.x * 16 + lane];
        uint4 X3 = x[(size_t)E3.x * 16 + lane];
        uint4 X4 = x[(size_t)E4.x * 16 + lane];
        uint4 X5 = x[(size_t)E5.x * 16 + lane];
        uint4 X6 = x[(size_t)E6.x * 16 + lane];
        uint4 X7 = x[(size_t)E7.x * 16 + lane];
        accum8(acc, X0, __int_as_float(E0.y));
        accum8(acc, X1, __int_as_float(E1.y));
        accum8(acc, X2, __int_as_float(E2.y));
        accum8(acc, X3, __int_as_float(E3.y));
        accum8(acc, X4, __int_as_float(E4.y));
        accum8(acc, X5, __int_as_float(E5.y));
        accum8(acc, X6, __int_as_float(E6.y));
        accum8(acc, X7, __int_as_float(E7.y));
    }
    for (; k + 4 <= e; k += 4) {
        int2 E0 = ep[k + 0], E1 = ep[k + 1], E2 = ep[k + 2], E3 = ep[k + 3];
        uint4 X0 = x[(size_t)E0.x * 16 + lane];
        uint4 X1 = x[(size_t)E1.x * 16 + lane];
        uint4 X2 = x[(size_t)E2.x * 16 + lane];
        uint4 X3 = x[(size_t)E3.x * 16 + lane];
        accum8(acc, X0, __int_as_float(E0.y));
        accum8(acc, X1, __int_as_float(E1.y));
        accum8(acc, X2, __int_as_float(E2.y));
        accum8(acc, X3, __int_as_float(E3.y));
    }
    for (; k < e; k++) {
        int2 E0 = ep[k];
        uint4 X0 = x[(size_t)E0.x * 16 + lane];
        accum8(acc, X0, __int_as_float(E0.y));
    }

    uint4 o;
    o.x = packbf(acc[0], acc[1]); o.y = packbf(acc[2], acc[3]);
    o.z = packbf(acc[4], acc[5]); o.w = packbf(acc[6], acc[7]);
    out[(size_t)g * 16 + lane] = o;
}

// ---------------------------------------------------------------------------
// Fused dense via bf16 MFMA 16x16x32. One 64-row slab per block (4 waves x
// 16 rows). Per order: stage W^T (32 KB) into LDS in [kc][n] layout, B-frags
// from LDS, A-frags direct from global (read-once). Per-row batchnorm via
// C-layout + shfl_xor{1,2,4,8}. No persistent loop (round-5 spill lesson).
// ---------------------------------------------------------------------------
__device__ __forceinline__ void bn_accum(
    f32x4* acc, const float* __restrict__ bias, const float* __restrict__ off,
    const float* __restrict__ sc, int i, float facc[8][4])
{
    float bc[8], sv[8], ov[8];
    #pragma unroll
    for (int ct = 0; ct < 8; ct++) {
        int c = ct * 16 + i;
        bc[ct] = bias[c]; sv[ct] = sc[c]; ov[ct] = off[c];
    }
    float s[4] = {0.f, 0.f, 0.f, 0.f};
    float qq[4] = {0.f, 0.f, 0.f, 0.f};
    #pragma unroll
    for (int ct = 0; ct < 8; ct++) {
        #pragma unroll
        for (int r = 0; r < 4; r++) {
            float v = fmaxf(acc[ct][r] + bc[ct], 0.f);
            acc[ct][r] = v;
            s[r] += v;
            qq[r] += v * v;
        }
    }
    #pragma unroll
    for (int r = 0; r < 4; r++) {
        #pragma unroll
        for (int m = 1; m <= 8; m <<= 1) {
            s[r]  += __shfl_xor(s[r],  m, 64);
            qq[r] += __shfl_xor(qq[r], m, 64);
        }
    }
    #pragma unroll
    for (int r = 0; r < 4; r++) {
        float mn = s[r] * 0.0078125f;
        float var = qq[r] * 0.0078125f - mn * mn;
        float rs = rsqrtf(var + 1e-9f);
        #pragma unroll
        for (int ct = 0; ct < 8; ct++)
            facc[ct][r] += sv[ct] * (acc[ct][r] - mn) * rs + ov[ct];
    }
}

__global__ __launch_bounds__(256) void fused_dense_mfma(
    const unsigned short* __restrict__ h0,
    const unsigned short* __restrict__ h1,
    const unsigned short* __restrict__ h2,
    const unsigned short* __restrict__ Wt,   // [3][128][128] bf16, [o][n][k]
    const float* __restrict__ b0, const float* __restrict__ b1,
    const float* __restrict__ b2,
    const float* __restrict__ off0, const float* __restrict__ off1,
    const float* __restrict__ off2,
    const float* __restrict__ sc0, const float* __restrict__ sc1,
    const float* __restrict__ sc2,
    float* __restrict__ out, int N)
{
    __shared__ uint4 Bl[2048];   // 32 KB: current order's W^T, (kc,n) at kc*128+n

    const int tid  = threadIdx.x;
    const int wave = tid >> 6;
    const int lane = tid & 63;
    const int i    = lane & 15;   // tile col / A-row
    const int q    = lane >> 4;   // quad
    const int slab = blockIdx.x * 64 + wave * 16;

    int arow = slab + i;
    if (arow >= N) arow = N - 1;

    const unsigned short* hops[3] = {h0, h1, h2};
    const float* bs[3]  = {b0, b1, b2};
    const float* ofs[3] = {off0, off1, off2};
    const float* scs[3] = {sc0, sc1, sc2};
    const bf16x8* Bv = (const bf16x8*)Bl;

    float facc[8][4];
    #pragma unroll
    for (int ct = 0; ct < 8; ct++)
        #pragma unroll
        for (int r = 0; r < 4; r++) facc[ct][r] = 0.f;

    for (int o = 0; o < 3; o++) {
        const uint4* Wg = (const uint4*)(Wt + o * DD * DD);
        #pragma unroll
        for (int j = 0; j < 8; j++) {
            int c  = j * 256 + tid;
            int nn = c & 127;
            int kc = c >> 7;
            Bl[kc * 128 + nn] = Wg[nn * 16 + kc];
        }
        __syncthreads();

        const unsigned short* arow_p = hops[o] + (size_t)arow * DD + q * 8;
        f32x4 acc[8];
        #pragma unroll
        for (int ct = 0; ct < 8; ct++) acc[ct] = (f32x4){0.f, 0.f, 0.f, 0.f};
        #pragma unroll
        for (int kb = 0; kb < 4; kb++) {
            bf16x8 a = *(const bf16x8*)(arow_p + kb * 32);
            const int kc = kb * 4 + q;
            #pragma unroll
            for (int ct = 0; ct < 8; ct++) {
                bf16x8 b = Bv[kc * 128 + ct * 16 + i];
                acc[ct] = __builtin_amdgcn_mfma_f32_16x16x32_bf16(a, b, acc[ct], 0, 0, 0);
            }
        }
        bn_accum(acc, bs[o], ofs[o], scs[o], i, facc);
        __syncthreads();
    }

    #pragma unroll
    for (int r = 0; r < 4; r++) {
        int orow = slab + q * 4 + r;
        if (orow < N) {
            float* op = out + (size_t)orow * DD + i;
            #pragma unroll
            for (int ct = 0; ct < 8; ct++) op[ct * 16] = facc[ct][r];
        }
    }
}

extern "C" void kernel_launch(void* const* d_in, const int* in_sizes, int n_in,
                              void* d_out, int out_size, void* d_ws, size_t ws_size,
                              hipStream_t stream)
{
    const float* vecs = (const float*)d_in[0];
    const float* adj  = (const float*)d_in[1];
    const int*   row  = (const int*)d_in[2];
    const int*   col  = (const int*)d_in[3];
    const float* W0   = (const float*)d_in[4];
    const float* b0   = (const float*)d_in[5];
    const float* off0 = (const float*)d_in[6];
    const float* sc0  = (const float*)d_in[7];
    const float* W1   = (const float*)d_in[8];
    const float* b1   = (const float*)d_in[9];
    const float* off1 = (const float*)d_in[10];
    const float* sc1  = (const float*)d_in[11];
    const float* W2   = (const float*)d_in[12];
    const float* b2   = (const float*)d_in[13];
    const float* off2 = (const float*)d_in[14];
    const float* sc2  = (const float*)d_in[15];

    const int E = in_sizes[1];
    const int N = NN;

    // Workspace layout (all regions 16B-aligned)
    unsigned short* hop1_bf = (unsigned short*)d_ws;          // N*DD bf16
    unsigned short* hop2_bf = hop1_bf + (size_t)N * DD;       // N*DD bf16
    unsigned short* vecs_bf = hop2_bf + (size_t)N * DD;       // N*DD bf16
    unsigned short* Wt_bf   = vecs_bf + (size_t)N * DD;       // 3*DD*DD bf16
    int*   row_ptr  = (int*)(Wt_bf + 3 * DD * DD);            // RP_PAD ints
    int*   bcnt     = row_ptr + RP_PAD;                       // 512
    int*   bbase    = bcnt + 512;                             // 512 (uses NB+1)
    int*   bcursor  = bbase + 512;                            // 512
    int2*  ep_raw   = (int2*)(bcursor + 512);                 // E
    int2*  epack    = ep_raw + E;                             // E

    hipMemsetAsync(bcnt, 0, NB * sizeof(int), stream);

    // Converters (independent of CSR build)
    const int n8 = N * DD / 8;
    cvt_bf16<<<(n8 + 255) / 256, 256, 0, stream>>>(
        (const float4*)vecs, (uint4*)vecs_bf, n8);
    cvt_w<<<8, 256, 0, stream>>>(W0, Wt_bf);
    cvt_w<<<8, 256, 0, stream>>>(W1, Wt_bf + DD * DD);
    cvt_w<<<8, 256, 0, stream>>>(W2, Wt_bf + 2 * DD * DD);

    // Bucketed CSR build
    const int cb = (E + 8191) / 8192;   // 196 chunks
    bucket_hist<<<cb, 256, 0, stream>>>(row, bcnt, E);
    bucket_scan<<<1, 512, 0, stream>>>(bcnt, bbase, bcursor);
    bucket_scatter<<<cb, 256, 0, stream>>>(row, col, adj, bcursor, ep_raw, E);
    bucket_to_csr<<<NB, 256, 0, stream>>>(bbase, ep_raw, row_ptr, epack, N, E);

    // SpMM hops (bf16 in/out, fp32 accumulate)
    int sb = (N * 16 + 255) / 256;
    spmm_bf16<<<sb, 256, 0, stream>>>(
        (const uint4*)vecs_bf, row_ptr, epack, (uint4*)hop1_bf, N);
    spmm_bf16<<<sb, 256, 0, stream>>>(
        (const uint4*)hop1_bf, row_ptr, epack, (uint4*)hop2_bf, N);

    // Fused dense (MFMA, per-order LDS-staged B)
    const int db = (N + 63) / 64;
    fused_dense_mfma<<<db, 256, 0, stream>>>(
        vecs_bf, hop1_bf, hop2_bf, Wt_bf,
        b0, b1, b2, off0, off1, off2, sc0, sc1, sc2,
        (float*)d_out, N);
}